// Round 4
// baseline (174.498 us; speedup 1.0000x reference)
//
#include <hip/hip_runtime.h>
#include <math.h>

#define NB 64
#define LIN 4001
#define LC 998
#define ND 1000
#define EPSBN 1e-5f

#define CK 96            // K-chunk for k_lin & k_out
#define NCH_LIN 11       // ceil(998/96)
#define NCH_OUT 11       // ceil(1000/96)

// ws float offsets
#define OFF_CONVT 0u        // 3*998*64      = 191616
#define OFF_PP    191616u   // 11*3*16*4096  = 2162688
#define OFF_CF    2354304u  // 1000*64       = 64000   (cfT[i][b])
#define OFF_OP    2418304u  // 11*16*4096    = 720896
// end = 3139200 floats = 12.6 MB

// ---------------- K1: fused BatchNorm + strided conv -> convT[w][j][b] ------
__global__ __launch_bounds__(256) void k_bnconv(
    const float* __restrict__ x,
    const float* __restrict__ g, const float* __restrict__ be,
    const float* __restrict__ mu, const float* __restrict__ va,
    const float* __restrict__ cwq, const float* __restrict__ cbq,
    const float* __restrict__ cwk, const float* __restrict__ cbk,
    const float* __restrict__ cwv, const float* __restrict__ cbv,
    float* __restrict__ convT)
{
    int j = blockIdx.x * 256 + threadIdx.x;
    int b = blockIdx.y;
    if (j >= LC) return;
    const float* xb = x + (size_t)b * LIN + 4 * j;
    float aq = 0.f, ak = 0.f, av = 0.f;
#pragma unroll
    for (int t = 0; t < 10; ++t) {
        int i = 4 * j + t;
        float s  = g[i] * rsqrtf(va[i] + EPSBN);
        float xn = (xb[t] - mu[i]) * s + be[i];
        aq = fmaf(xn, cwq[t], aq);
        ak = fmaf(xn, cwk[t], ak);
        av = fmaf(xn, cwv[t], av);
    }
    convT[((size_t)0 * LC + j) * 64 + b] = aq + cbq[0];
    convT[((size_t)1 * LC + j) * 64 + b] = ak + cbk[0];
    convT[((size_t)2 * LC + j) * 64 + b] = av + cbv[0];
}

// ---------------- shared GEMM microtile body (64b x 64d x CK), no atomics ---
__device__ __forceinline__ void gemm_tile(
    const float* __restrict__ Asrc,   // [jc][64] chunk, b-contiguous
    const float* __restrict__ Brow,   // weight base, row stride ldB
    int ldB, int dgb, int j0, int jc,
    float* __restrict__ Pt,           // output tile [64 b][64 d]
    float* lds)
{
    float* ldsC = lds;                // [96][64]  = 6144
    float* ldsW = lds + 6144;         // [64][97]  = 6208
    int tid  = threadIdx.x;
    int lane = tid & 63;
    int w    = tid >> 6;
    int b0   = (lane & 7) << 3;
    int d0   = (lane >> 3) << 3;

    {   // stage A chunk via float4 (fully coalesced)
        const float4* src = (const float4*)Asrc;
        float4* dst = (float4*)ldsC;
        for (int t = tid; t < jc * 16; t += 256) dst[t] = src[t];
    }
    // stage B tile via float2 (row strides even): 64 rows x 48 f2
    for (int idx = tid; idx < 3072; idx += 256) {
        int dd = idx / 48, j2 = idx % 48;
        int dg = dgb + dd;
        float2 v = make_float2(0.f, 0.f);
        if (dg < ND && 2 * j2 < jc)
            v = *(const float2*)(Brow + (size_t)dg * ldB + j0 + 2 * j2);
        ldsW[dd * 97 + 2 * j2]     = v.x;
        ldsW[dd * 97 + 2 * j2 + 1] = v.y;
    }
    __syncthreads();

    float acc[8][8];
#pragma unroll
    for (int i = 0; i < 8; ++i)
#pragma unroll
        for (int jx = 0; jx < 8; ++jx) acc[i][jx] = 0.f;

    int js = (jc * w) >> 2;
    int je = (jc * (w + 1)) >> 2;
    for (int jj = js; jj < je; ++jj) {
        float4 c0 = *(const float4*)(ldsC + jj * 64 + b0);
        float4 c1 = *(const float4*)(ldsC + jj * 64 + b0 + 4);
        float cv[8] = {c0.x, c0.y, c0.z, c0.w, c1.x, c1.y, c1.z, c1.w};
        float wv[8];
#pragma unroll
        for (int r = 0; r < 8; ++r) wv[r] = ldsW[(d0 + r) * 97 + jj];
#pragma unroll
        for (int i = 0; i < 8; ++i)
#pragma unroll
            for (int jx = 0; jx < 8; ++jx)
                acc[i][jx] = fmaf(cv[i], wv[jx], acc[i][jx]);
    }
    __syncthreads();   // done with staged data; reuse LDS for reduce

    // two passes (f4 halves of each lane's d-range); per-wave buf [64][36]
    for (int p = 0; p < 2; ++p) {
        float* red = lds + w * 2304;
#pragma unroll
        for (int i = 0; i < 8; ++i)
            *(float4*)(red + (b0 + i) * 36 + (d0 >> 1)) =
                make_float4(acc[i][4*p], acc[i][4*p+1], acc[i][4*p+2], acc[i][4*p+3]);
        __syncthreads();
        for (int t = tid; t < 512; t += 256) {
            int bb = t >> 3, gg = t & 7;
            int o = bb * 36 + 4 * gg;
            float4 a0 = *(const float4*)(lds + o);
            float4 a1 = *(const float4*)(lds + 2304 + o);
            float4 a2 = *(const float4*)(lds + 4608 + o);
            float4 a3 = *(const float4*)(lds + 6912 + o);
            float4 s;
            s.x = a0.x + a1.x + a2.x + a3.x;
            s.y = a0.y + a1.y + a2.y + a3.y;
            s.z = a0.z + a1.z + a2.z + a3.z;
            s.w = a0.w + a1.w + a2.w + a3.w;
            *(float4*)(Pt + bb * 64 + 8 * gg + 4 * p) = s;
        }
        __syncthreads();
    }
}

// ---------------- K2: QKV GEMM partials -> Pp -------------------------------
__global__ __launch_bounds__(256) void k_lin(
    const float* __restrict__ convT,
    const float* __restrict__ lwq, const float* __restrict__ lwk,
    const float* __restrict__ lwv,
    float* __restrict__ Pp)
{
    __shared__ float lds[12352];
    int dgb   = blockIdx.x * 64;
    int which = blockIdx.y;
    int chunk = blockIdx.z;
    int j0 = chunk * CK;
    int jc = (LC - j0 < CK) ? (LC - j0) : CK;
    const float* lw = (which == 0) ? lwq : ((which == 1) ? lwk : lwv);
    const float* Asrc = convT + ((size_t)which * LC + j0) * 64;
    float* Pt = Pp + (((size_t)chunk * 3 + which) * 16 + blockIdx.x) * 4096;
    gemm_tile(Asrc, lw, LC, dgb, j0, jc, Pt, lds);
}

// ---------------- K3: fused Pp-reduce + bias/ReLU/in_proj + attention -------
// grid (8 i-tiles of 128, 64 b). Reduces k,v,q from Pp in-block, then
// online softmax (scores never materialized), writes cfT[i][b] w/ out_proj.
__global__ __launch_bounds__(256) void k_attn(
    const float* __restrict__ Pp,
    const float* __restrict__ lbq, const float* __restrict__ lbk,
    const float* __restrict__ lbv,
    const float* __restrict__ ipw, const float* __restrict__ ipb,
    const float* __restrict__ opw, const float* __restrict__ opb,
    float* __restrict__ cfT)
{
    __shared__ float skv[2000];   // interleaved [k*log2e, v] per j
    __shared__ float sql[128];
    __shared__ float sd[512];
    __shared__ float sn[512];
    __shared__ float rmax[4];
    __shared__ float rmin[4];
    const float LOG2E = 1.4426950408889634f;
    int tid  = threadIdx.x;
    int b    = blockIdx.y;
    int i0   = blockIdx.x * 128;
    int w    = tid >> 6;
    int lane = tid & 63;

    float ipw1 = ipw[1], ipb1 = ipb[1];
    float ipw2 = ipw[2], ipb2 = ipb[2];

    // phase 1: reduce k,v over chunks; apply bias/relu/in_proj; stage to LDS
    for (int j = tid; j < ND; j += 256) {
        int it = j >> 6, il = j & 63;
        size_t base = ((size_t)it) * 4096 + (b << 6) + il;
        float sk = 0.f, sv = 0.f;
        for (int c = 0; c < NCH_LIN; ++c) {
            sk += Pp[((size_t)(c * 3 + 1) * 16) * 4096 + base];
            sv += Pp[((size_t)(c * 3 + 2) * 16) * 4096 + base];
        }
        float yk = fmaxf(sk + lbk[j], 0.f) * ipw1 + ipb1;
        float yv = fmaxf(sv + lbv[j], 0.f) * ipw2 + ipb2;
        skv[2 * j]     = yk * LOG2E;
        skv[2 * j + 1] = yv;
    }
    // q for this block's 128 rows
    if (tid < 128) {
        int i = i0 + tid;
        float sq = 0.f;
        if (i < ND) {
            int it = i >> 6, il = i & 63;
            size_t base = ((size_t)it) * 4096 + (b << 6) + il;
            for (int c = 0; c < NCH_LIN; ++c)
                sq += Pp[((size_t)(c * 3 + 0) * 16) * 4096 + base];
            sq = fmaxf(sq + lbq[i], 0.f) * ipw[0] + ipb[0];
        }
        sql[tid] = sq;
    }
    __syncthreads();

    // phase 2: kmax/kmin over skv[2j] (log2e-scaled k; scale>0 so order kept)
    float km = -INFINITY, kn = INFINITY;
    for (int j = tid; j < ND; j += 256) {
        float f = skv[2 * j];
        km = fmaxf(km, f);
        kn = fminf(kn, f);
    }
#pragma unroll
    for (int off = 1; off < 64; off <<= 1) {
        km = fmaxf(km, __shfl_xor(km, off));
        kn = fminf(kn, __shfl_xor(kn, off));
    }
    if (lane == 0) { rmax[w] = km; rmin[w] = kn; }
    __syncthreads();
    km = fmaxf(fmaxf(rmax[0], rmax[1]), fmaxf(rmax[2], rmax[3]));
    kn = fminf(fminf(rmin[0], rmin[1]), fminf(rmin[2], rmin[3]));

    // phase 3: exp2 loop; each wave covers 250 j, each thread 2 i-rows
    float q0 = sql[lane];
    float q1 = sql[64 + lane];
    float m0 = (q0 >= 0.f) ? q0 * km : q0 * kn;
    float m1 = (q1 >= 0.f) ? q1 * km : q1 * kn;
    const float2* kv2 = (const float2*)skv;
    int jb = w * 250;
    float d0a = 0.f, n0a = 0.f, d1a = 0.f, n1a = 0.f;
#pragma unroll 2
    for (int jl = 0; jl < 250; ++jl) {
        float2 f = kv2[jb + jl];          // broadcast ds_read_b64
        float e0 = exp2f(fmaf(q0, f.x, -m0));
        float e1 = exp2f(fmaf(q1, f.x, -m1));
        d0a += e0; n0a = fmaf(e0, f.y, n0a);
        d1a += e1; n1a = fmaf(e1, f.y, n1a);
    }
    sd[w * 128 + lane]      = d0a;
    sd[w * 128 + 64 + lane] = d1a;
    sn[w * 128 + lane]      = n0a;
    sn[w * 128 + 64 + lane] = n1a;
    __syncthreads();

    if (tid < 128) {
        int i = i0 + tid;
        if (i < ND) {
            float dt = sd[tid] + sd[128 + tid] + sd[256 + tid] + sd[384 + tid];
            float nt = sn[tid] + sn[128 + tid] + sn[256 + tid] + sn[384 + tid];
            cfT[(size_t)i * 64 + b] = (nt / dt) * opw[0] + opb[0];
        }
    }
}

// ---------------- K4: out GEMM partials -> Op -------------------------------
__global__ __launch_bounds__(256) void k_out(
    const float* __restrict__ cfT, const float* __restrict__ W,
    float* __restrict__ Op)
{
    __shared__ float lds[12352];
    int egb   = blockIdx.x * 64;
    int chunk = blockIdx.y;
    int j0 = chunk * CK;
    int jc = (ND - j0 < CK) ? (ND - j0) : CK;
    const float* Asrc = cfT + (size_t)j0 * 64;
    float* Pt = Op + ((size_t)chunk * 16 + blockIdx.x) * 4096;
    gemm_tile(Asrc, W, ND, egb, j0, jc, Pt, lds);
}

// ---------------- K5: reduce Op chunks + bias -> out ------------------------
__global__ __launch_bounds__(256) void k_fin(
    const float* __restrict__ Op, const float* __restrict__ outb,
    float* __restrict__ out)
{
    int e = blockIdx.x * 256 + threadIdx.x;
    int b = blockIdx.y;
    if (e >= ND) return;
    float s = outb[e];
    size_t cell = ((size_t)(e >> 6)) * 4096 + (b << 6) + (e & 63);
    for (int c = 0; c < NCH_OUT; ++c)
        s += Op[(size_t)c * 16 * 4096 + cell];
    out[(size_t)b * ND + e] = s;
}

extern "C" void kernel_launch(void* const* d_in, const int* in_sizes, int n_in,
                              void* d_out, int out_size, void* d_ws, size_t ws_size,
                              hipStream_t stream)
{
    const float* x    = (const float*)d_in[0];
    const float* g    = (const float*)d_in[1];
    const float* be   = (const float*)d_in[2];
    const float* mu   = (const float*)d_in[3];
    const float* va   = (const float*)d_in[4];
    const float* cwq  = (const float*)d_in[5];
    const float* cbq  = (const float*)d_in[6];
    const float* lwq  = (const float*)d_in[7];
    const float* lbq  = (const float*)d_in[8];
    const float* cwk  = (const float*)d_in[9];
    const float* cbk  = (const float*)d_in[10];
    const float* lwk  = (const float*)d_in[11];
    const float* lbk  = (const float*)d_in[12];
    const float* cwv  = (const float*)d_in[13];
    const float* cbv  = (const float*)d_in[14];
    const float* lwv  = (const float*)d_in[15];
    const float* lbv  = (const float*)d_in[16];
    const float* ipw  = (const float*)d_in[17];
    const float* ipb  = (const float*)d_in[18];
    const float* opw  = (const float*)d_in[19];
    const float* opb  = (const float*)d_in[20];
    const float* W    = (const float*)d_in[21];
    const float* outb = (const float*)d_in[22];

    float* ws    = (float*)d_ws;
    float* convT = ws + OFF_CONVT;
    float* Pp    = ws + OFF_PP;
    float* cfT   = ws + OFF_CF;
    float* Op    = ws + OFF_OP;
    float* out   = (float*)d_out;

    k_bnconv<<<dim3(4, 64), 256, 0, stream>>>(x, g, be, mu, va,
                                              cwq, cbq, cwk, cbk, cwv, cbv, convT);
    k_lin  <<<dim3(16, 3, NCH_LIN), 256, 0, stream>>>(convT, lwq, lwk, lwv, Pp);
    k_attn <<<dim3(8, 64), 256, 0, stream>>>(Pp, lbq, lbk, lbv, ipw, ipb,
                                             opw, opb, cfT);
    k_out  <<<dim3(16, NCH_OUT), 256, 0, stream>>>(cfT, W, Op);
    k_fin  <<<dim3(4, 64), 256, 0, stream>>>(Op, outb, out);
}